// Round 12
// baseline (161.205 us; speedup 1.0000x reference)
//
#include <hip/hip_runtime.h>
#include <hip/hip_bf16.h>

#define KK 7
#define NL1 8
#define NL2 8
#define IMG 128
#define REG 32            // region edge (pixels) per workgroup
#define RT 38             // o1 tile edge = REG + 6
#define O1P 40            // o1 padded pitch (160B, 16B-aligned; exact fit, reads <= col 39)
#define XR 44             // xt real rows/cols = REG + 12
#define XTP 44            // xt pitch = 44 (176B, 16B-aligned; exact fit, real reads <= col 43)
#define NBINS 64
#define NHB 16            // histogram blocks per region (4x4 of 8x8)

// Correctness contract (matches XLA-CPU f32 reference, verified round 6):
//  conv1: per-pixel strict sequential FMA chain, taps ordered dp->dq->c(fastest)
//  out1 : materialized as f32 (and zeroed outside the image = conv2 padding)
//  conv2: per-filter strict sequential FMA chain, taps ordered dp->dq
// Restructuring only changes WHERE operands come from, never per-chain order.
//
// Round-12: histogram atomics were the dominant LDS-conflict source (packing
// two ADJACENT BINS of one block per word doubled same-word collisions:
// 1.28e7 -> 2.2e7). Now (a) bins of one block never share a word — pack
// ACROSS blocks: word = bin*8 + (blk>>1), half = blk&1; (b) per-thread
// RUN-MERGE: the 4 pixels of a thread sit in one 8x8 block and often share
// a code -> merge equal-bin runs into one atomicAdd(cnt<<sh). Max count per
// half = 64 << 2^16: no carry into the neighboring halfword.

#define LDX12(dst, plane, row, col)                                          \
    { float4 t_;                                                             \
      t_ = *(const float4*)&xt[plane][row][col];                             \
      dst[0]=t_.x; dst[1]=t_.y; dst[2]=t_.z; dst[3]=t_.w;                    \
      t_ = *(const float4*)&xt[plane][row][(col)+4];                         \
      dst[4]=t_.x; dst[5]=t_.y; dst[6]=t_.z; dst[7]=t_.w;                    \
      t_ = *(const float4*)&xt[plane][row][(col)+8];                         \
      dst[8]=t_.x; dst[9]=t_.y; dst[10]=t_.z; dst[11]=t_.w; }

#define C1TAPS(acc0, acc1, acc2, acc3, dp)                                   \
    _Pragma("unroll")                                                        \
    for (int dq = 0; dq < KK; ++dq) {                                        \
        float wa = w1g[(dp) * 7 + dq];                                       \
        float wb = w1g[49 + (dp) * 7 + dq];                                  \
        float wc = w1g[98 + (dp) * 7 + dq];                                  \
        acc0 = __builtin_fmaf(f0[dq + 0], wa, acc0);                         \
        acc0 = __builtin_fmaf(f1[dq + 0], wb, acc0);                         \
        acc0 = __builtin_fmaf(f2[dq + 0], wc, acc0);                         \
        acc1 = __builtin_fmaf(f0[dq + 1], wa, acc1);                         \
        acc1 = __builtin_fmaf(f1[dq + 1], wb, acc1);                         \
        acc1 = __builtin_fmaf(f2[dq + 1], wc, acc1);                         \
        acc2 = __builtin_fmaf(f0[dq + 2], wa, acc2);                         \
        acc2 = __builtin_fmaf(f1[dq + 2], wb, acc2);                         \
        acc2 = __builtin_fmaf(f2[dq + 2], wc, acc2);                         \
        acc3 = __builtin_fmaf(f0[dq + 3], wa, acc3);                         \
        acc3 = __builtin_fmaf(f1[dq + 3], wb, acc3);                         \
        acc3 = __builtin_fmaf(f2[dq + 3], wc, acc3);                         \
    }

__global__ __launch_bounds__(256, 5) void pcanet_fused(
    const float* __restrict__ x,    // (32,3,128,128)
    const float* __restrict__ w1,   // (8,3,7,7)
    const float* __restrict__ w2,   // (8,1,7,7)
    float* __restrict__ out)        // (32, 8*256*64)
{
    const int tid = threadIdx.x;        // 0..255
    const int reg = blockIdx.x;         // 0..15 : 4x4 regions
    const int ch  = blockIdx.y;         // L1 filter index
    const int n   = blockIdx.z;         // image index
    const int P0  = (reg >> 2) * REG;   // region row origin
    const int Q0  = (reg & 3) * REG;    // region col origin

    __shared__ __align__(16) float xt[3][XR][XTP];   // zero-padded x tile (23.2KB)
    __shared__ __align__(16) float o1[RT][O1P];      // f32 conv1 tile (6.1KB)
    __shared__ unsigned int hist[NBINS * 8];         // word=bin*8+(blk>>1), half=blk&1 (2KB)

    const float* __restrict__ w1g = w1 + ch * 147;   // wave-uniform -> s_load
    const float* __restrict__ w2g = w2;              // wave-uniform -> s_load

    // ---- xt fill: lane = tile col (coalesced), rows wave-strided ----
    {
        const int lane = tid & 63;
        const int wv   = tid >> 6;      // 0..3
        const float* xn = x + (size_t)n * 3 * IMG * IMG;
        const int gs = Q0 - 6 + lane;   // global col for this lane
        const bool cok = (gs >= 0) && (gs < IMG);
        if (lane < XTP) {
            for (int c = 0; c < 3; ++c)
                for (int r = wv; r < XR; r += 4) {
                    int gr = P0 - 6 + r;
                    float v = 0.0f;
                    if (cok && gr >= 0 && gr < IMG)
                        v = xn[((size_t)c * IMG + gr) * IMG + gs];
                    xt[c][r][lane] = v;
                }
        }
    }
    for (int i = tid; i < NBINS * 8; i += 256) hist[i] = 0u;
    __syncthreads();

    // ---- conv1: 19 row-pairs x 10 col-chunks = 190 tasks, single pass ----
    if (tid < 190) {
        int pr = tid / 10;             // row-pair index 0..18
        int c1 = 4 * (tid % 10);       // o1 col base 0..36 (16B-aligned)
        int r0 = 2 * pr;               // o1 rows r0, r0+1
        float a0 = 0.f, a1 = 0.f, a2 = 0.f, a3 = 0.f;   // row r0
        float b0 = 0.f, b1 = 0.f, b2 = 0.f, b3 = 0.f;   // row r0+1
        #pragma unroll
        for (int e = 0; e < 8; ++e) {
            float f0[12], f1[12], f2[12];
            LDX12(f0, 0, r0 + e, c1)
            LDX12(f1, 1, r0 + e, c1)
            LDX12(f2, 2, r0 + e, c1)
            if (e < 7) { C1TAPS(a0, a1, a2, a3, e) }       // row0: dp = e
            if (e >= 1) { C1TAPS(b0, b1, b2, b3, e - 1) }  // row1: dp = e-1
        }
        // mask out-of-image o1 pixels to exact 0 (conv2's zero padding)
        int gs0 = Q0 - 3 + c1;
        bool c0ok = (gs0 + 0 >= 0 && gs0 + 0 < IMG);
        bool c1ok = (gs0 + 1 >= 0 && gs0 + 1 < IMG);
        bool c2ok = (gs0 + 2 >= 0 && gs0 + 2 < IMG);
        bool c3ok = (gs0 + 3 >= 0 && gs0 + 3 < IMG);
        {
            int gr = P0 - 3 + r0;
            bool rok = (gr >= 0 && gr < IMG);
            float4 st;
            st.x = (rok && c0ok) ? a0 : 0.f;
            st.y = (rok && c1ok) ? a1 : 0.f;
            st.z = (rok && c2ok) ? a2 : 0.f;
            st.w = (rok && c3ok) ? a3 : 0.f;
            *(float4*)&o1[r0][c1] = st;
        }
        {
            int gr = P0 - 3 + r0 + 1;
            bool rok = (gr >= 0 && gr < IMG);
            float4 st;
            st.x = (rok && c0ok) ? b0 : 0.f;
            st.y = (rok && c1ok) ? b1 : 0.f;
            st.z = (rok && c2ok) ? b2 : 0.f;
            st.w = (rok && c3ok) ? b3 : 0.f;
            *(float4*)&o1[r0 + 1][c1] = st;
        }
    }
    __syncthreads();

    // ---- conv2: thread owns 4 adjacent pixels (r, c0..c0+3) ----
    {
        const int r  = tid >> 3;          // 0..31 output row in region
        const int c0 = (tid & 7) * 4;     // 0..28 output col base (16B-aligned)
        float acc[NL2][4];
        #pragma unroll
        for (int l = 0; l < NL2; ++l)
            #pragma unroll
            for (int k = 0; k < 4; ++k) acc[l][k] = 0.f;

        for (int dp = 0; dp < KK; ++dp) {
            float f[12];
            { float4 t_;
              t_ = *(const float4*)&o1[r + dp][c0];
              f[0]=t_.x; f[1]=t_.y; f[2]=t_.z; f[3]=t_.w;
              t_ = *(const float4*)&o1[r + dp][c0 + 4];
              f[4]=t_.x; f[5]=t_.y; f[6]=t_.z; f[7]=t_.w;
              t_ = *(const float4*)&o1[r + dp][c0 + 8];
              f[8]=t_.x; f[9]=t_.y; f[10]=t_.z; f[11]=t_.w; }
            #pragma unroll
            for (int l = 0; l < NL2; ++l)
                #pragma unroll
                for (int dq = 0; dq < KK; ++dq) {
                    float w = w2g[l * 49 + dp * 7 + dq];   // uniform scalar
                    acc[l][0] = __builtin_fmaf(f[dq + 0], w, acc[l][0]);
                    acc[l][1] = __builtin_fmaf(f[dq + 1], w, acc[l][1]);
                    acc[l][2] = __builtin_fmaf(f[dq + 2], w, acc[l][2]);
                    acc[l][3] = __builtin_fmaf(f[dq + 3], w, acc[l][3]);
                }
        }
        // ---- bins for the 4 pixels (all in ONE 8x8 block) + run-merge ----
        int bins[4];
        #pragma unroll
        for (int k = 0; k < 4; ++k) {
            int code = 0;
            #pragma unroll
            for (int l = 0; l < NL2; ++l)
                if (acc[l][k] > 0.0f) code |= (1 << l);
            bins[k] = code >> 2;                       // 0..63
        }
        const int blkid = (r >> 3) * 4 + (c0 >> 3);    // same for k=0..3
        const int pair  = blkid >> 1;
        const unsigned sh = 16u * (unsigned)(blkid & 1);
        unsigned cnt = 1;
        int prev = bins[0];
        if (bins[1] == prev) ++cnt;
        else { atomicAdd(&hist[prev * 8 + pair], cnt << sh); prev = bins[1]; cnt = 1; }
        if (bins[2] == prev) ++cnt;
        else { atomicAdd(&hist[prev * 8 + pair], cnt << sh); prev = bins[2]; cnt = 1; }
        if (bins[3] == prev) ++cnt;
        else { atomicAdd(&hist[prev * 8 + pair], cnt << sh); prev = bins[3]; cnt = 1; }
        atomicAdd(&hist[prev * 8 + pair], cnt << sh);
    }
    __syncthreads();

    // ---- write out 16 blocks x 64 bins (unpack halfwords) ----
    size_t planeBase = ((size_t)(n * NL1 + ch)) * 256 * NBINS;
    for (int i = tid; i < NHB * NBINS; i += 256) {
        int bl = i >> 6, bin = i & 63;
        unsigned int w = hist[bin * 8 + (bl >> 1)];
        unsigned int cnt = (w >> (16 * (bl & 1))) & 0xFFFFu;
        int br = bl >> 2, bc = bl & 3;
        int blkg = ((P0 >> 3) + br) * 16 + ((Q0 >> 3) + bc);
        out[planeBase + (size_t)blkg * NBINS + bin] = (float)cnt;
    }
}

extern "C" void kernel_launch(void* const* d_in, const int* in_sizes, int n_in,
                              void* d_out, int out_size, void* d_ws, size_t ws_size,
                              hipStream_t stream) {
    const float* x  = (const float*)d_in[0];
    const float* w1 = (const float*)d_in[1];
    const float* w2 = (const float*)d_in[2];
    float* out = (float*)d_out;

    dim3 grid(16, NL1, 32);   // (4x4 regions, 8 L1 channels, 32 images)
    dim3 block(256);
    pcanet_fused<<<grid, block, 0, stream>>>(x, w1, w2, out);
}

// Round 13
// 85.208 us; speedup vs baseline: 1.8919x; 1.8919x over previous
//
#include <hip/hip_runtime.h>
#include <hip/hip_bf16.h>

#define KK 7
#define NL1 8
#define NL2 8
#define IMG 128
#define REG 32            // region edge (pixels) per workgroup
#define RT 38             // o1 tile edge = REG + 6
#define O1P 40            // o1 padded pitch (160B, 16B-aligned; exact fit, reads <= col 39)
#define XR 44             // xt real rows/cols = REG + 12
#define XTP 44            // xt pitch = 44 (176B, 16B-aligned; exact fit, real reads <= col 43)
#define NBINS 64
#define NHB 16            // histogram blocks per region (4x4 of 8x8)
#define HST 33            // hist block stride in words: bank = (blk + bin>>1) mod 32

// Correctness contract (matches XLA-CPU f32 reference, verified round 6):
//  conv1: per-pixel strict sequential FMA chain, taps ordered dp->dq->c(fastest)
//  out1 : materialized as f32 (and zeroed outside the image = conv2 padding)
//  conv2: per-filter strict sequential FMA chain, taps ordered dp->dq
// Restructuring only changes WHERE operands come from, never per-chain order.
//
// Round-13: reverted round-12's run-merge + bin-major layout (it spilled ~240B
// /thread to scratch: FETCH 11->132MB, WRITE 20->238MB, dur 82->161us).
// Single change vs round-11: hist block stride 32 -> 33 words, so the 4
// blocks a wave touches map to 4 DISTINCT banks (was: same bank for equal
// bin>>1 -> guaranteed 4-way serialize on every histogram atomic).
// Max count/halfword = 64 << 2^16: no carry into the neighbor bin.

#define LDX12(dst, plane, row, col)                                          \
    { float4 t_;                                                             \
      t_ = *(const float4*)&xt[plane][row][col];                             \
      dst[0]=t_.x; dst[1]=t_.y; dst[2]=t_.z; dst[3]=t_.w;                    \
      t_ = *(const float4*)&xt[plane][row][(col)+4];                         \
      dst[4]=t_.x; dst[5]=t_.y; dst[6]=t_.z; dst[7]=t_.w;                    \
      t_ = *(const float4*)&xt[plane][row][(col)+8];                         \
      dst[8]=t_.x; dst[9]=t_.y; dst[10]=t_.z; dst[11]=t_.w; }

#define C1TAPS(acc0, acc1, acc2, acc3, dp)                                   \
    _Pragma("unroll")                                                        \
    for (int dq = 0; dq < KK; ++dq) {                                        \
        float wa = w1g[(dp) * 7 + dq];                                       \
        float wb = w1g[49 + (dp) * 7 + dq];                                  \
        float wc = w1g[98 + (dp) * 7 + dq];                                  \
        acc0 = __builtin_fmaf(f0[dq + 0], wa, acc0);                         \
        acc0 = __builtin_fmaf(f1[dq + 0], wb, acc0);                         \
        acc0 = __builtin_fmaf(f2[dq + 0], wc, acc0);                         \
        acc1 = __builtin_fmaf(f0[dq + 1], wa, acc1);                         \
        acc1 = __builtin_fmaf(f1[dq + 1], wb, acc1);                         \
        acc1 = __builtin_fmaf(f2[dq + 1], wc, acc1);                         \
        acc2 = __builtin_fmaf(f0[dq + 2], wa, acc2);                         \
        acc2 = __builtin_fmaf(f1[dq + 2], wb, acc2);                         \
        acc2 = __builtin_fmaf(f2[dq + 2], wc, acc2);                         \
        acc3 = __builtin_fmaf(f0[dq + 3], wa, acc3);                         \
        acc3 = __builtin_fmaf(f1[dq + 3], wb, acc3);                         \
        acc3 = __builtin_fmaf(f2[dq + 3], wc, acc3);                         \
    }

__global__ __launch_bounds__(256, 5) void pcanet_fused(
    const float* __restrict__ x,    // (32,3,128,128)
    const float* __restrict__ w1,   // (8,3,7,7)
    const float* __restrict__ w2,   // (8,1,7,7)
    float* __restrict__ out)        // (32, 8*256*64)
{
    const int tid = threadIdx.x;        // 0..255
    const int reg = blockIdx.x;         // 0..15 : 4x4 regions
    const int ch  = blockIdx.y;         // L1 filter index
    const int n   = blockIdx.z;         // image index
    const int P0  = (reg >> 2) * REG;   // region row origin
    const int Q0  = (reg & 3) * REG;    // region col origin

    __shared__ __align__(16) float xt[3][XR][XTP];   // zero-padded x tile (23.2KB)
    __shared__ __align__(16) float o1[RT][O1P];      // f32 conv1 tile (6.1KB)
    __shared__ unsigned int hist[NHB * HST];         // blk*33 + bin>>1, half=bin&1 (2.1KB)

    const float* __restrict__ w1g = w1 + ch * 147;   // wave-uniform -> s_load
    const float* __restrict__ w2g = w2;              // wave-uniform -> s_load

    // ---- xt fill: lane = tile col (coalesced), rows wave-strided ----
    {
        const int lane = tid & 63;
        const int wv   = tid >> 6;      // 0..3
        const float* xn = x + (size_t)n * 3 * IMG * IMG;
        const int gs = Q0 - 6 + lane;   // global col for this lane
        const bool cok = (gs >= 0) && (gs < IMG);
        if (lane < XTP) {
            for (int c = 0; c < 3; ++c)
                for (int r = wv; r < XR; r += 4) {
                    int gr = P0 - 6 + r;
                    float v = 0.0f;
                    if (cok && gr >= 0 && gr < IMG)
                        v = xn[((size_t)c * IMG + gr) * IMG + gs];
                    xt[c][r][lane] = v;
                }
        }
    }
    for (int i = tid; i < NHB * HST; i += 256) hist[i] = 0u;
    __syncthreads();

    // ---- conv1: 19 row-pairs x 10 col-chunks = 190 tasks, single pass ----
    if (tid < 190) {
        int pr = tid / 10;             // row-pair index 0..18
        int c1 = 4 * (tid % 10);       // o1 col base 0..36 (16B-aligned)
        int r0 = 2 * pr;               // o1 rows r0, r0+1
        float a0 = 0.f, a1 = 0.f, a2 = 0.f, a3 = 0.f;   // row r0
        float b0 = 0.f, b1 = 0.f, b2 = 0.f, b3 = 0.f;   // row r0+1
        #pragma unroll
        for (int e = 0; e < 8; ++e) {
            float f0[12], f1[12], f2[12];
            LDX12(f0, 0, r0 + e, c1)
            LDX12(f1, 1, r0 + e, c1)
            LDX12(f2, 2, r0 + e, c1)
            if (e < 7) { C1TAPS(a0, a1, a2, a3, e) }       // row0: dp = e
            if (e >= 1) { C1TAPS(b0, b1, b2, b3, e - 1) }  // row1: dp = e-1
        }
        // mask out-of-image o1 pixels to exact 0 (conv2's zero padding)
        int gs0 = Q0 - 3 + c1;
        bool c0ok = (gs0 + 0 >= 0 && gs0 + 0 < IMG);
        bool c1ok = (gs0 + 1 >= 0 && gs0 + 1 < IMG);
        bool c2ok = (gs0 + 2 >= 0 && gs0 + 2 < IMG);
        bool c3ok = (gs0 + 3 >= 0 && gs0 + 3 < IMG);
        {
            int gr = P0 - 3 + r0;
            bool rok = (gr >= 0 && gr < IMG);
            float4 st;
            st.x = (rok && c0ok) ? a0 : 0.f;
            st.y = (rok && c1ok) ? a1 : 0.f;
            st.z = (rok && c2ok) ? a2 : 0.f;
            st.w = (rok && c3ok) ? a3 : 0.f;
            *(float4*)&o1[r0][c1] = st;
        }
        {
            int gr = P0 - 3 + r0 + 1;
            bool rok = (gr >= 0 && gr < IMG);
            float4 st;
            st.x = (rok && c0ok) ? b0 : 0.f;
            st.y = (rok && c1ok) ? b1 : 0.f;
            st.z = (rok && c2ok) ? b2 : 0.f;
            st.w = (rok && c3ok) ? b3 : 0.f;
            *(float4*)&o1[r0 + 1][c1] = st;
        }
    }
    __syncthreads();

    // ---- conv2: thread owns 4 adjacent pixels (r, c0..c0+3) ----
    {
        const int r  = tid >> 3;          // 0..31 output row in region
        const int c0 = (tid & 7) * 4;     // 0..28 output col base (16B-aligned)
        float acc[NL2][4];
        #pragma unroll
        for (int l = 0; l < NL2; ++l)
            #pragma unroll
            for (int k = 0; k < 4; ++k) acc[l][k] = 0.f;

        for (int dp = 0; dp < KK; ++dp) {
            float f[12];
            { float4 t_;
              t_ = *(const float4*)&o1[r + dp][c0];
              f[0]=t_.x; f[1]=t_.y; f[2]=t_.z; f[3]=t_.w;
              t_ = *(const float4*)&o1[r + dp][c0 + 4];
              f[4]=t_.x; f[5]=t_.y; f[6]=t_.z; f[7]=t_.w;
              t_ = *(const float4*)&o1[r + dp][c0 + 8];
              f[8]=t_.x; f[9]=t_.y; f[10]=t_.z; f[11]=t_.w; }
            #pragma unroll
            for (int l = 0; l < NL2; ++l)
                #pragma unroll
                for (int dq = 0; dq < KK; ++dq) {
                    float w = w2g[l * 49 + dp * 7 + dq];   // uniform scalar
                    acc[l][0] = __builtin_fmaf(f[dq + 0], w, acc[l][0]);
                    acc[l][1] = __builtin_fmaf(f[dq + 1], w, acc[l][1]);
                    acc[l][2] = __builtin_fmaf(f[dq + 2], w, acc[l][2]);
                    acc[l][3] = __builtin_fmaf(f[dq + 3], w, acc[l][3]);
                }
        }
        #pragma unroll
        for (int k = 0; k < 4; ++k) {
            int code = 0;
            #pragma unroll
            for (int l = 0; l < NL2; ++l)
                if (acc[l][k] > 0.0f) code |= (1 << l);
            int bin = code >> 2;                       // 0..63
            int bc = (c0 + k) >> 3, br = r >> 3;
            atomicAdd(&hist[(br * 4 + bc) * HST + (bin >> 1)],
                      1u << (16 * (bin & 1)));
        }
    }
    __syncthreads();

    // ---- write out 16 blocks x 64 bins (unpack halfwords) ----
    size_t planeBase = ((size_t)(n * NL1 + ch)) * 256 * NBINS;
    for (int i = tid; i < NHB * NBINS; i += 256) {
        int bl = i >> 6, bin = i & 63;
        unsigned int w = hist[bl * HST + (bin >> 1)];
        unsigned int cnt = (w >> (16 * (bin & 1))) & 0xFFFFu;
        int br = bl >> 2, bc = bl & 3;
        int blkg = ((P0 >> 3) + br) * 16 + ((Q0 >> 3) + bc);
        out[planeBase + (size_t)blkg * NBINS + bin] = (float)cnt;
    }
}

extern "C" void kernel_launch(void* const* d_in, const int* in_sizes, int n_in,
                              void* d_out, int out_size, void* d_ws, size_t ws_size,
                              hipStream_t stream) {
    const float* x  = (const float*)d_in[0];
    const float* w1 = (const float*)d_in[1];
    const float* w2 = (const float*)d_in[2];
    float* out = (float*)d_out;

    dim3 grid(16, NL1, 32);   // (4x4 regions, 8 L1 channels, 32 images)
    dim3 block(256);
    pcanet_fused<<<grid, block, 0, stream>>>(x, w1, w2, out);
}